// Round 16
// baseline (219.754 us; speedup 1.0000x reference)
//
#include <hip/hip_runtime.h>

#define BATCH   4096
#define IN_SZ   512
#define NQ      12
#define OUT_SZ  256
#define DEPTH   3
#define NST     4096   // 2^NQ
#define BN_EPS  1e-5f
#define INV_B   (1.f / 4096.f)

// ---- ws layout (in floats) ----
#define OFF_ENC    0            // 49152
#define OFF_BN1M   49152        // 16
#define OFF_BN1R   49168        // 16
#define OFF_GU2    49184        // DEPTH*12*16 = 576 (dup/neg packed U gates)
#define OFF_GC2    49760        // DEPTH*11*4 = 132 (pad 160) {c,c,s,s} per CRY
#define OFF_GF2    49920        // DEPTH*9*16 = 432 (dup/neg packed fused Ry*U)
#define OFF_PROBS  50352        // 49152
#define OFF_ACC90  99504        // 90 compact moment accumulators (pad 96)
#define OFF_RSTD   99600        // 256
#define OFF_PMEAN  99856        // 16

typedef float v2f __attribute__((ext_vector_type(2)));
typedef float v4f __attribute__((ext_vector_type(4)));
#define SW2(a) __builtin_shufflevector(a, a, 1, 0)

__device__ __forceinline__ void make_u(const float* rr, float* u) {
    float ax = rr[0] * 0.5f, ay = rr[1] * 0.5f, az = rr[2] * 0.5f;
    float cx = cosf(ax), sx = sinf(ax);
    float cy = cosf(ay), sy = sinf(ay);
    float cz = cosf(az), sz = sinf(az);
    float m00r =  cy * cx, m00i =  sy * sx;
    float m01r = -sy * cx, m01i = -cy * sx;
    float m10r =  sy * cx, m10i = -cy * sx;
    float m11r =  cy * cx, m11i = -sy * sx;
    u[0] = cz * m00r + sz * m00i;  u[1] = cz * m00i - sz * m00r;
    u[2] = cz * m01r + sz * m01i;  u[3] = cz * m01i - sz * m01r;
    u[4] = cz * m10r - sz * m10i;  u[5] = cz * m10i + sz * m10r;
    u[6] = cz * m11r - sz * m11i;  u[7] = cz * m11i + sz * m11r;
}

__device__ __forceinline__ void store_dup(float* o, const float* u) {
    // packed layout: {u0,u0},{-u1,u1},{u2,u2},{-u3,u3},{u4,u4},{-u5,u5},{u6,u6},{-u7,u7}
    o[0] = u[0];  o[1] = u[0];   o[2] = -u[1];  o[3] = u[1];
    o[4] = u[2];  o[5] = u[2];   o[6] = -u[3];  o[7] = u[3];
    o[8] = u[4];  o[9] = u[4];   o[10] = -u[5]; o[11] = u[5];
    o[12] = u[6]; o[13] = u[6];  o[14] = -u[7]; o[15] = u[7];
}

// ================= K1: encode, wave-per-row (+ gate tables & accum zero in block 1024) =======
__global__ void k_encode(const float* __restrict__ x, const float* __restrict__ w,
                         const float* __restrict__ bvec,
                         const float* __restrict__ rot, const float* __restrict__ ent,
                         float* __restrict__ enc, float* __restrict__ gU2,
                         float* __restrict__ gC2, float* __restrict__ gF2,
                         float* __restrict__ acc90) {
    if (blockIdx.x == 1024) {
        int t = threadIdx.x;
        if (t < DEPTH * NQ) {                      // plain U gates, dup layout
            float u[8];
            make_u(rot + t * 3, u);
            store_dup(gU2 + t * 16, u);
        }
        if (t >= 64 && t - 64 < DEPTH * (NQ - 1)) { // CRY coeffs {c,c,s,s}
            int i = t - 64;
            float th = ent[i] * 0.5f;
            float c = cosf(th), s = sinf(th);
            float* o = gC2 + i * 4;
            o[0] = c; o[1] = c; o[2] = s; o[3] = s;
        }
        if (t >= 128 && t - 128 < DEPTH * 9) {      // fused Ry*U products, dup layout
            int i = t - 128;
            int l = i / 9, k = i % 9;
            int c = k + k / 3;                      // 0,1,2,4,5,6,8,9,10
            float u[8];
            make_u(rot + (l * NQ + c + 1) * 3, u);
            float th = ent[l * (NQ - 1) + c] * 0.5f;
            float c_ = cosf(th), s_ = sinf(th);
            float f[8];
            f[0] = c_ * u[0] - s_ * u[4];  f[1] = c_ * u[1] - s_ * u[5];
            f[2] = c_ * u[2] - s_ * u[6];  f[3] = c_ * u[3] - s_ * u[7];
            f[4] = s_ * u[0] + c_ * u[4];  f[5] = s_ * u[1] + c_ * u[5];
            f[6] = s_ * u[2] + c_ * u[6];  f[7] = s_ * u[3] + c_ * u[7];
            store_dup(gF2 + i * 16, f);
        }
        if (t >= 160 && t - 160 < 90) acc90[t - 160] = 0.f;   // zero moment accumulators
        return;
    }
    int t = threadIdx.x;
    int wv = t >> 6, lane = t & 63;
    int row = blockIdx.x * 4 + wv;              // 1024 blocks x 4 waves = 4096 rows
    const float4* xr = (const float4*)(x + row * IN_SZ) + lane * 2;
    float4 xa = xr[0], xb = xr[1];
    float acc[NQ];
    #pragma unroll
    for (int q = 0; q < NQ; q++) {
        const float4* wr = (const float4*)(w + q * IN_SZ) + lane * 2;
        float4 wa = wr[0], wb = wr[1];
        float d = xa.x*wa.x + xa.y*wa.y + xa.z*wa.z + xa.w*wa.w
                + xb.x*wb.x + xb.y*wb.y + xb.z*wb.z + xb.w*wb.w;
        #pragma unroll
        for (int o = 32; o > 0; o >>= 1) d += __shfl_down(d, o, 64);
        acc[q] = d;
    }
    if (lane == 0) {
        float* er = enc + row * NQ;
        #pragma unroll
        for (int q = 0; q < NQ; q++) er[q] = acc[q] + bvec[q];
    }
}

// ---------------- block-wide sum for 256-thread blocks (broadcast) ----------------
__device__ float blockAllSum(float v, float* scr) {
    #pragma unroll
    for (int o = 32; o > 0; o >>= 1) v += __shfl_down(v, o, 64);
    int lane = threadIdx.x & 63, w = threadIdx.x >> 6;
    __syncthreads();
    if (lane == 0) scr[w] = v;
    __syncthreads();
    return scr[0] + scr[1] + scr[2] + scr[3];
}

// ================= K2: batchnorm1 stats — single pass, 1024 threads =================
__global__ void k_bnstats(const float* __restrict__ xm, float* __restrict__ mo,
                          float* __restrict__ ro) {
    __shared__ float scr[32];
    int j = blockIdx.x, t = threadIdx.x;
    float s = 0.f, s2 = 0.f;
    for (int b = t; b < BATCH; b += 1024) {
        float v = xm[b * NQ + j];
        s += v; s2 += v * v;
    }
    #pragma unroll
    for (int o = 32; o > 0; o >>= 1) { s += __shfl_down(s, o, 64); s2 += __shfl_down(s2, o, 64); }
    int lane = t & 63, w = t >> 6;
    if (lane == 0) { scr[w] = s; scr[16 + w] = s2; }
    __syncthreads();
    if (t == 0) {
        float S = 0.f, S2 = 0.f;
        #pragma unroll
        for (int i = 0; i < 16; i++) { S += scr[i]; S2 += scr[16 + i]; }
        float mean = S / (float)BATCH;
        float var  = S2 / (float)BATCH - mean * mean;
        mo[j] = mean;
        ro[j] = 1.f / sqrtf(var + BN_EPS);
    }
}

// ================= K3: quantum circuit — 3-pass schedule + CRY fusion + packed tables ========
// Canonical amp index: qubit q at bit (11-q). Swizzle: slot = idx ^ (((idx>>5)&7)<<1).
// Window A: local bits 3..0 (qubits 8-11, b128); B: bits 7..4; C: bits 11..8.
// 3-pass layer schedule C->B->A by commutation (R14); CRY->U fusion (R15).
// Gate coeffs pre-duplicated/pre-negated in ws -> loaded as v2f via uniform s_load
// (SGPR-pair VOP3P operands; no splat/neg VALU).
// Moment tail: compact atomics into acc90 (zeroed by k_encode's block 1024; R11-measured).
// LESSONS (measured): R10 — no offset hoisting / waves_per_eu attrs. R12 — no 128B-padded
// atomics. R11 — no grid-scaled redundant stats math in k_final.
#define SLA2(j) ((T << 4) | ((((j) ^ ((T >> 1) & 7))) << 1))
#define SLB(m)  (((T & 0xF0) << 4) | ((m) << 4) | ((T & 15) ^ ((m) & 14)))
#define SLC(m)  (((m) << 8) | (T ^ ((((T >> 5) & 7)) << 1)))

#define LDA(j, Ra, Rb) { v4f t_ = *(const v4f*)(xch + SLA2(j));                 \
    Ra = __builtin_shufflevector(t_, t_, 0, 1);                                 \
    Rb = __builtin_shufflevector(t_, t_, 2, 3); }
#define STA(j, Ra, Rb) { v4f t_ = __builtin_shufflevector(Ra, Rb, 0, 1, 2, 3);  \
    *(v4f*)(xch + SLA2(j)) = t_; }

#define LOADA do { LDA(0,s0,s1) LDA(1,s2,s3) LDA(2,s4,s5) LDA(3,s6,s7)          \
    LDA(4,s8,s9) LDA(5,s10,s11) LDA(6,s12,s13) LDA(7,s14,s15) } while (0)
#define STORA do { STA(0,s0,s1) STA(1,s2,s3) STA(2,s4,s5) STA(3,s6,s7)          \
    STA(4,s8,s9) STA(5,s10,s11) STA(6,s12,s13) STA(7,s14,s15) } while (0)

#define LOADW(SL) do {                                                          \
    s0=xch[SL(0)];  s1=xch[SL(1)];  s2=xch[SL(2)];  s3=xch[SL(3)];              \
    s4=xch[SL(4)];  s5=xch[SL(5)];  s6=xch[SL(6)];  s7=xch[SL(7)];              \
    s8=xch[SL(8)];  s9=xch[SL(9)];  s10=xch[SL(10)]; s11=xch[SL(11)];           \
    s12=xch[SL(12)]; s13=xch[SL(13)]; s14=xch[SL(14)]; s15=xch[SL(15)]; } while (0)
#define STORW(SL) do {                                                          \
    xch[SL(0)]=s0;  xch[SL(1)]=s1;  xch[SL(2)]=s2;  xch[SL(3)]=s3;              \
    xch[SL(4)]=s4;  xch[SL(5)]=s5;  xch[SL(6)]=s6;  xch[SL(7)]=s7;              \
    xch[SL(8)]=s8;  xch[SL(9)]=s9;  xch[SL(10)]=s10; xch[SL(11)]=s11;           \
    xch[SL(12)]=s12; xch[SL(13)]=s13; xch[SL(14)]=s14; xch[SL(15)]=s15; } while (0)

// packed-table loads: each coeff is a ready-made v2f ({u,u} or {-u,u})
#define U_LOADP(uptr) const v2f* u_ = (const v2f*)(uptr);                        \
    v2f c00r = u_[0], c00i = u_[1], c01r = u_[2], c01i = u_[3],                  \
        c10r = u_[4], c10i = u_[5], c11r = u_[6], c11i = u_[7];
#define U_LOADF(uptr) const v2f* f_ = (const v2f*)(uptr);                        \
    v2f d00r = f_[0], d00i = f_[1], d01r = f_[2], d01i = f_[3],                  \
        d10r = f_[4], d10i = f_[5], d11r = f_[6], d11i = f_[7];

#define U_PAIRP(A, B) { v2f a0 = A, a1 = B, a0s = SW2(a0), a1s = SW2(a1);        \
    A = a0*c00r + a0s*c00i + a1*c01r + a1s*c01i;                                 \
    B = a0*c10r + a0s*c10i + a1*c11r + a1s*c11i; }
#define U_PAIRF(A, B) { v2f a0 = A, a1 = B, a0s = SW2(a0), a1s = SW2(a1);        \
    A = a0*d00r + a0s*d00i + a1*d01r + a1s*d01i;                                 \
    B = a0*d10r + a0s*d10i + a1*d11r + a1s*d11i; }

#define APPLY_U_K3(uptr) do { U_LOADP(uptr)                                      \
    U_PAIRP(s0,s8) U_PAIRP(s1,s9) U_PAIRP(s2,s10) U_PAIRP(s3,s11)                \
    U_PAIRP(s4,s12) U_PAIRP(s5,s13) U_PAIRP(s6,s14) U_PAIRP(s7,s15) } while (0)

// fused: gate on bit2, coeff set selected by pair's bit3
#define APPLY_UF_K2(uP, uF) do { U_LOADP(uP) U_LOADF(uF)                         \
    U_PAIRP(s0,s4) U_PAIRP(s1,s5) U_PAIRP(s2,s6) U_PAIRP(s3,s7)                  \
    U_PAIRF(s8,s12) U_PAIRF(s9,s13) U_PAIRF(s10,s14) U_PAIRF(s11,s15) } while (0)
// fused: gate on bit1, selected by bit2
#define APPLY_UF_K1(uP, uF) do { U_LOADP(uP) U_LOADF(uF)                         \
    U_PAIRP(s0,s2) U_PAIRP(s1,s3) U_PAIRF(s4,s6) U_PAIRF(s5,s7)                  \
    U_PAIRP(s8,s10) U_PAIRP(s9,s11) U_PAIRF(s12,s14) U_PAIRF(s13,s15) } while (0)
// fused: gate on bit0, selected by bit1
#define APPLY_UF_K0(uP, uF) do { U_LOADP(uP) U_LOADF(uF)                         \
    U_PAIRP(s0,s1) U_PAIRF(s2,s3) U_PAIRP(s4,s5) U_PAIRF(s6,s7)                  \
    U_PAIRP(s8,s9) U_PAIRF(s10,s11) U_PAIRP(s12,s13) U_PAIRF(s14,s15) } while (0)

#define RY_PAIRP(A, B) { v2f a0 = A, a1 = B;                                     \
    A = a0*cc2 - a1*ss2;  B = a0*ss2 + a1*cc2; }
#define RYALL_K3(cptr) do { const v2f* cp_ = (const v2f*)(cptr);                 \
    v2f cc2 = cp_[0], ss2 = cp_[1];                                              \
    RY_PAIRP(s0,s8) RY_PAIRP(s1,s9) RY_PAIRP(s2,s10) RY_PAIRP(s3,s11)            \
    RY_PAIRP(s4,s12) RY_PAIRP(s5,s13) RY_PAIRP(s6,s14) RY_PAIRP(s7,s15) } while (0)

// init in window C order: idx = m<<8 | T; qubits 0-3 from m bits 3..0
#define INITJC(SR, j) { SR.x = f * (((j)&8)?qs0:qc0) * (((j)&4)?qs1:qc1)         \
    * (((j)&2)?qs2:qc2) * (((j)&1)?qs3:qc3); SR.y = 0.f; }
#define PRJ(S) ((S).x*(S).x + (S).y*(S).y)
#define WREDUCE(v) { v += __shfl_down(v,32,64); v += __shfl_down(v,16,64);       \
    v += __shfl_down(v,8,64); v += __shfl_down(v,4,64);                          \
    v += __shfl_down(v,2,64); v += __shfl_down(v,1,64); }

#define MKQ(i) float qc##i, qs##i; {                                             \
    float h_ = h##i;                                                             \
    float a_ = nz ? h_ * rinv : h_;                                              \
    float amp_ = fminf(fabsf(a_), 1.f);                                          \
    qc##i = sqrtf(fmaxf(1.f - amp_ * amp_, 0.f));                                \
    qs##i = (a_ < 0.f) ? -amp_ : amp_; }

__launch_bounds__(256)
__global__ void k_quantum(const float* __restrict__ enc,
                          const float* __restrict__ bn1m, const float* __restrict__ bn1r,
                          const float* __restrict__ g1, const float* __restrict__ b1,
                          const float* __restrict__ gU2, const float* __restrict__ gC2,
                          const float* __restrict__ gF2,
                          float* __restrict__ probs, float* __restrict__ acc90) {
    __shared__ __align__(16) v2f xch[NST];                        // exactly 32 KB

    int T = threadIdx.x, b = blockIdx.x;

    // ---- BN1 + tanh + qv, all uniform scalars computed in registers ----
    const float* er = enc + b * NQ;
    float h0  = tanhf(g1[0]  * (er[0]  - bn1m[0])  * bn1r[0]  + b1[0]);
    float h1  = tanhf(g1[1]  * (er[1]  - bn1m[1])  * bn1r[1]  + b1[1]);
    float h2  = tanhf(g1[2]  * (er[2]  - bn1m[2])  * bn1r[2]  + b1[2]);
    float h3  = tanhf(g1[3]  * (er[3]  - bn1m[3])  * bn1r[3]  + b1[3]);
    float h4  = tanhf(g1[4]  * (er[4]  - bn1m[4])  * bn1r[4]  + b1[4]);
    float h5  = tanhf(g1[5]  * (er[5]  - bn1m[5])  * bn1r[5]  + b1[5]);
    float h6  = tanhf(g1[6]  * (er[6]  - bn1m[6])  * bn1r[6]  + b1[6]);
    float h7  = tanhf(g1[7]  * (er[7]  - bn1m[7])  * bn1r[7]  + b1[7]);
    float h8  = tanhf(g1[8]  * (er[8]  - bn1m[8])  * bn1r[8]  + b1[8]);
    float h9  = tanhf(g1[9]  * (er[9]  - bn1m[9])  * bn1r[9]  + b1[9]);
    float h10 = tanhf(g1[10] * (er[10] - bn1m[10]) * bn1r[10] + b1[10]);
    float h11 = tanhf(g1[11] * (er[11] - bn1m[11]) * bn1r[11] + b1[11]);
    float n2 = h0*h0+h1*h1+h2*h2+h3*h3+h4*h4+h5*h5+h6*h6+h7*h7
             + h8*h8+h9*h9+h10*h10+h11*h11;
    float norm = sqrtf(n2);
    bool  nz   = norm > 0.f;
    float rinv = 1.f / fmaxf(norm, 1e-30f);
    MKQ(0) MKQ(1) MKQ(2) MKQ(3) MKQ(4) MKQ(5) MKQ(6) MKQ(7)
    MKQ(8) MKQ(9) MKQ(10) MKQ(11)

    v2f s0, s1, s2, s3, s4, s5, s6, s7, s8, s9, s10, s11, s12, s13, s14, s15;

    // ---- pass C, layer 0: init + U0 + fused(U1,CRY0) + fused(U2,CRY1) + fused(U3,CRY2) ----
    {
        float f = ((T>>7)&1 ? qs4 : qc4) * ((T>>6)&1 ? qs5 : qc5)
                * ((T>>5)&1 ? qs6 : qc6) * ((T>>4)&1 ? qs7 : qc7)
                * ((T>>3)&1 ? qs8 : qc8) * ((T>>2)&1 ? qs9 : qc9)
                * ((T>>1)&1 ? qs10 : qc10) * ((T>>0)&1 ? qs11 : qc11);
        INITJC(s0,0)  INITJC(s1,1)  INITJC(s2,2)  INITJC(s3,3)
        INITJC(s4,4)  INITJC(s5,5)  INITJC(s6,6)  INITJC(s7,7)
        INITJC(s8,8)  INITJC(s9,9)  INITJC(s10,10) INITJC(s11,11)
        INITJC(s12,12) INITJC(s13,13) INITJC(s14,14) INITJC(s15,15)
        APPLY_U_K3(gU2 + 0 * 16);
        APPLY_UF_K2(gU2 + 1 * 16, gF2 + 0 * 16);
        APPLY_UF_K1(gU2 + 2 * 16, gF2 + 1 * 16);
        APPLY_UF_K0(gU2 + 3 * 16, gF2 + 2 * 16);
        STORW(SLC);
    }
    __syncthreads();                          // C->B crosses waves

    #pragma unroll 1
    for (int l = 0; l < DEPTH; l++) {
        const float* UL = gU2 + l * 192;
        const float* CL = gC2 + l * 44;
        const float* FL = gF2 + l * 144;
        // ---- window B: U4 + CRY3(pred) + fused(U5,CRY4) + fused(U6,CRY5) + fused(U7,CRY6) ----
        LOADW(SLB);
        APPLY_U_K3(UL + 4 * 16);
        if (T & 16) RYALL_K3(CL + 3 * 4);     // CRY3 (ctrl = idx bit 8)
        APPLY_UF_K2(UL + 5 * 16, FL + 3 * 16);
        APPLY_UF_K1(UL + 6 * 16, FL + 4 * 16);
        APPLY_UF_K0(UL + 7 * 16, FL + 5 * 16);
        STORW(SLB);
        __builtin_amdgcn_wave_barrier();      // B->A is wave-private
        // ---- window A: U8 + CRY7(pred) + fused(U9,CRY8) + fused(U10,CRY9) + fused(U11,CRY10) ----
        LOADA;
        APPLY_U_K3(UL + 8 * 16);
        if (T & 1) RYALL_K3(CL + 7 * 4);      // CRY7 (ctrl = idx bit 4)
        APPLY_UF_K2(UL + 9 * 16, FL + 6 * 16);
        APPLY_UF_K1(UL + 10 * 16, FL + 7 * 16);
        APPLY_UF_K0(UL + 11 * 16, FL + 8 * 16);
        if (l < DEPTH - 1) {
            STORA;
            __syncthreads();                  // A->C crosses waves
            // ---- window C, layer l+1: U0 + fused CRY0-2 ----
            const float* UN = gU2 + (l + 1) * 192;
            const float* FN = gF2 + (l + 1) * 144;
            LOADW(SLC);
            APPLY_U_K3(UN + 0 * 16);
            APPLY_UF_K2(UN + 1 * 16, FN + 0 * 16);
            APPLY_UF_K1(UN + 2 * 16, FN + 1 * 16);
            APPLY_UF_K0(UN + 3 * 16, FN + 2 * 16);
            STORW(SLC);
            __syncthreads();                  // C->B crosses waves
        }
    }

    // ---- marginals from registers (window A: idx = T<<4 | m) ----
    float p0 = PRJ(s0),  p1 = PRJ(s1),  p2 = PRJ(s2),  p3 = PRJ(s3);
    float p4 = PRJ(s4),  p5 = PRJ(s5),  p6 = PRJ(s6),  p7 = PRJ(s7);
    float p8 = PRJ(s8),  p9 = PRJ(s9),  p10 = PRJ(s10), p11 = PRJ(s11);
    float p12 = PRJ(s12), p13 = PRJ(s13), p14 = PRJ(s14), p15 = PRJ(s15);
    float tot = p0+p1+p2+p3+p4+p5+p6+p7+p8+p9+p10+p11+p12+p13+p14+p15;
    float r8  = p8+p9+p10+p11+p12+p13+p14+p15;
    float r9  = p4+p5+p6+p7+p12+p13+p14+p15;
    float r10 = p2+p3+p6+p7+p10+p11+p14+p15;
    float r11 = p1+p3+p5+p7+p9+p11+p13+p15;
    float r0 = (T & 128) ? tot : 0.f;
    float r1 = (T & 64)  ? tot : 0.f;
    float r2 = (T & 32)  ? tot : 0.f;
    float r3 = (T & 16)  ? tot : 0.f;
    float r4 = (T & 8)   ? tot : 0.f;
    float r5 = (T & 4)   ? tot : 0.f;
    float r6 = (T & 2)   ? tot : 0.f;
    float r7 = (T & 1)   ? tot : 0.f;

    WREDUCE(r0) WREDUCE(r1) WREDUCE(r2) WREDUCE(r3) WREDUCE(r4) WREDUCE(r5)
    WREDUCE(r6) WREDUCE(r7) WREDUCE(r8) WREDUCE(r9) WREDUCE(r10) WREDUCE(r11)

    __syncthreads();                     // xch no longer needed as state
    float* red = (float*)xch;
    int lane = T & 63, w = T >> 6;
    if (lane == 0) {
        float* rr = red + w * NQ;
        rr[0]=r0; rr[1]=r1; rr[2]=r2; rr[3]=r3; rr[4]=r4; rr[5]=r5;
        rr[6]=r6; rr[7]=r7; rr[8]=r8; rr[9]=r9; rr[10]=r10; rr[11]=r11;
    }
    __syncthreads();
    float* pq = red + 64;
    if (T < NQ) {
        float v = red[T] + red[NQ + T] + red[2 * NQ + T] + red[3 * NQ + T];
        probs[b * NQ + T] = v;
        pq[T] = v;
    }
    __syncthreads();
    // ---- moment accumulation: 12 sums + 78 pair products (q <= q2), compact ----
    if (T < 90) {
        float v;
        if (T < NQ) {
            v = pq[T];
        } else {
            int j = T - NQ, q = 0;
            while (j >= NQ - q) { j -= NQ - q; q++; }
            v = pq[q] * pq[q + j];
        }
        unsafeAtomicAdd(acc90 + T, v);
    }
}

// ================= K4: pmean/cov/rstd from moments (one block) =================
__global__ void k_rstd(const float* __restrict__ acc90, const float* __restrict__ dw,
                       float* __restrict__ pmean, float* __restrict__ rstd) {
    __shared__ float pm[NQ];
    __shared__ float cv[NQ * NQ];
    int t = threadIdx.x;
    if (t < NQ) {
        float m = acc90[t] * INV_B;
        pm[t] = m;
        pmean[t] = m;
    }
    __syncthreads();
    if (t < NQ * NQ) {
        int q = t / NQ, q2 = t - q * NQ;
        int lo = q < q2 ? q : q2, hi = q < q2 ? q2 : q;
        float P = acc90[NQ + lo * NQ - (lo * (lo - 1)) / 2 + (hi - lo)];
        cv[t] = P * INV_B - pm[q] * pm[q2];
    }
    __syncthreads();
    float w[NQ];
    #pragma unroll
    for (int q = 0; q < NQ; q++) w[q] = dw[t * NQ + q];
    float var = 0.f;
    #pragma unroll
    for (int q = 0; q < NQ; q++) {
        float a = 0.f;
        #pragma unroll
        for (int q2 = 0; q2 < NQ; q2++) a += cv[q * NQ + q2] * w[q2];
        var += w[q] * a;
    }
    rstd[t] = 1.f / sqrtf(var + BN_EPS);
}

// ================= K5: final decode + BN2 (2 rows per block) =================
__global__ void k_final(const float* __restrict__ probs, const float* __restrict__ pmean,
                        const float* __restrict__ rstd, const float* __restrict__ dw,
                        const float* __restrict__ g2, const float* __restrict__ b2,
                        float* __restrict__ out) {
    __shared__ float cp[2][NQ];
    int b0 = blockIdx.x * 2;
    int t = threadIdx.x;
    int half = t >> 8, j = t & 255;
    if (t < NQ)                      cp[0][t]       = probs[b0 * NQ + t]        - pmean[t];
    else if (t >= 256 && t < 256+NQ) cp[1][t - 256] = probs[(b0+1) * NQ + t-256] - pmean[t - 256];
    __syncthreads();
    float acc = 0.f;
    #pragma unroll
    for (int q = 0; q < NQ; q++) acc += cp[half][q] * dw[j * NQ + q];
    out[(b0 + half) * OUT_SZ + j] = acc * rstd[j] * g2[j] + b2[j];
}

extern "C" void kernel_launch(void* const* d_in, const int* in_sizes, int n_in,
                              void* d_out, int out_size, void* d_ws, size_t ws_size,
                              hipStream_t stream) {
    const float* x     = (const float*)d_in[0];
    const float* enc_w = (const float*)d_in[1];
    const float* enc_b = (const float*)d_in[2];
    const float* rot   = (const float*)d_in[3];
    const float* ent   = (const float*)d_in[4];
    const float* dec_w = (const float*)d_in[5];
    // d_in[6] = dec_b — cancels inside BN2
    const float* g1    = (const float*)d_in[7];
    const float* b1    = (const float*)d_in[8];
    const float* g2    = (const float*)d_in[9];
    const float* b2    = (const float*)d_in[10];

    float* ws    = (float*)d_ws;
    float* enc   = ws + OFF_ENC;
    float* bn1m  = ws + OFF_BN1M;
    float* bn1r  = ws + OFF_BN1R;
    float* gU2   = ws + OFF_GU2;
    float* gC2   = ws + OFF_GC2;
    float* gF2   = ws + OFF_GF2;
    float* prb   = ws + OFF_PROBS;
    float* acc90 = ws + OFF_ACC90;
    float* rstd  = ws + OFF_RSTD;
    float* pmean = ws + OFF_PMEAN;

    hipLaunchKernelGGL(k_encode, dim3(1025), dim3(256), 0, stream,
                       x, enc_w, enc_b, rot, ent, enc, gU2, gC2, gF2, acc90);
    hipLaunchKernelGGL(k_bnstats, dim3(NQ), dim3(1024), 0, stream, enc, bn1m, bn1r);
    hipLaunchKernelGGL(k_quantum, dim3(BATCH), dim3(256), 0, stream,
                       enc, bn1m, bn1r, g1, b1, gU2, gC2, gF2, prb, acc90);
    hipLaunchKernelGGL(k_rstd, dim3(1), dim3(OUT_SZ), 0, stream,
                       acc90, dec_w, pmean, rstd);
    hipLaunchKernelGGL(k_final, dim3(BATCH / 2), dim3(512), 0, stream,
                       prb, pmean, rstd, dec_w, g2, b2, (float*)d_out);
}

// Round 17
// 215.610 us; speedup vs baseline: 1.0192x; 1.0192x over previous
//
#include <hip/hip_runtime.h>

#define BATCH   4096
#define IN_SZ   512
#define NQ      12
#define OUT_SZ  256
#define DEPTH   3
#define NST     4096   // 2^NQ
#define BN_EPS  1e-5f
#define INV_B   (1.f / 4096.f)

// ---- ws layout (in floats) ----
#define OFF_ENC    0            // 49152
#define OFF_BN1M   49152
#define OFF_BN1R   49168
#define OFF_GU     49184        // 288
#define OFF_GC     49472        // 66 (pad 96)
#define OFF_GF     49568        // DEPTH*9*8 = 216 (pad 224): fused Ry*U products
#define OFF_PROBS  49792        // 49152
#define OFF_ACC90  98944        // 90 compact moment accumulators (pad 96)
#define OFF_RSTD   99040        // 256
#define OFF_PMEAN  99296        // 16

typedef float v2f __attribute__((ext_vector_type(2)));
typedef float v4f __attribute__((ext_vector_type(4)));
#define SW2(a) __builtin_shufflevector(a, a, 1, 0)

__device__ __forceinline__ void make_u(const float* rr, float* u) {
    float ax = rr[0] * 0.5f, ay = rr[1] * 0.5f, az = rr[2] * 0.5f;
    float cx = cosf(ax), sx = sinf(ax);
    float cy = cosf(ay), sy = sinf(ay);
    float cz = cosf(az), sz = sinf(az);
    float m00r =  cy * cx, m00i =  sy * sx;
    float m01r = -sy * cx, m01i = -cy * sx;
    float m10r =  sy * cx, m10i = -cy * sx;
    float m11r =  cy * cx, m11i = -sy * sx;
    u[0] = cz * m00r + sz * m00i;  u[1] = cz * m00i - sz * m00r;
    u[2] = cz * m01r + sz * m01i;  u[3] = cz * m01i - sz * m01r;
    u[4] = cz * m10r - sz * m10i;  u[5] = cz * m10i + sz * m10r;
    u[6] = cz * m11r - sz * m11i;  u[7] = cz * m11i + sz * m11r;
}

// ================= K1: encode, wave-per-row (+ gates & accum zero in block 1024) =============
__global__ void k_encode(const float* __restrict__ x, const float* __restrict__ w,
                         const float* __restrict__ bvec,
                         const float* __restrict__ rot, const float* __restrict__ ent,
                         float* __restrict__ enc, float* __restrict__ gU, float* __restrict__ gC,
                         float* __restrict__ gF, float* __restrict__ acc90) {
    if (blockIdx.x == 1024) {
        int t = threadIdx.x;
        if (t < DEPTH * NQ) {
            float u[8];
            make_u(rot + t * 3, u);
            float* o = gU + t * 8;
            #pragma unroll
            for (int i = 0; i < 8; i++) o[i] = u[i];
        }
        if (t >= 64 && t - 64 < DEPTH * (NQ - 1)) {
            int i = t - 64;
            float th = ent[i] * 0.5f;
            gC[i * 2 + 0] = cosf(th);
            gC[i * 2 + 1] = sinf(th);
        }
        // fused products P = Ry(theta_c) * U_{c+1} for c in {0,1,2, 4,5,6, 8,9,10}
        if (t >= 128 && t - 128 < DEPTH * 9) {
            int i = t - 128;              // 0..26
            int l = i / 9, k = i % 9;
            int c = k + k / 3;            // 0,1,2,4,5,6,8,9,10
            float u[8];
            make_u(rot + (l * NQ + c + 1) * 3, u);
            float th = ent[l * (NQ - 1) + c] * 0.5f;
            float c_ = cosf(th), s_ = sinf(th);
            float* o = gF + i * 8;
            o[0] = c_ * u[0] - s_ * u[4];  o[1] = c_ * u[1] - s_ * u[5];
            o[2] = c_ * u[2] - s_ * u[6];  o[3] = c_ * u[3] - s_ * u[7];
            o[4] = s_ * u[0] + c_ * u[4];  o[5] = s_ * u[1] + c_ * u[5];
            o[6] = s_ * u[2] + c_ * u[6];  o[7] = s_ * u[3] + c_ * u[7];
        }
        if (t >= 160 && t - 160 < 90) acc90[t - 160] = 0.f;   // zero moment accumulators
        return;
    }
    int t = threadIdx.x;
    int wv = t >> 6, lane = t & 63;
    int row = blockIdx.x * 4 + wv;              // 1024 blocks x 4 waves = 4096 rows
    const float4* xr = (const float4*)(x + row * IN_SZ) + lane * 2;
    float4 xa = xr[0], xb = xr[1];
    float acc[NQ];
    #pragma unroll
    for (int q = 0; q < NQ; q++) {
        const float4* wr = (const float4*)(w + q * IN_SZ) + lane * 2;
        float4 wa = wr[0], wb = wr[1];
        float d = xa.x*wa.x + xa.y*wa.y + xa.z*wa.z + xa.w*wa.w
                + xb.x*wb.x + xb.y*wb.y + xb.z*wb.z + xb.w*wb.w;
        #pragma unroll
        for (int o = 32; o > 0; o >>= 1) d += __shfl_down(d, o, 64);
        acc[q] = d;
    }
    if (lane == 0) {
        float* er = enc + row * NQ;
        #pragma unroll
        for (int q = 0; q < NQ; q++) er[q] = acc[q] + bvec[q];
    }
}

// ---------------- block-wide sum for 256-thread blocks (broadcast) ----------------
__device__ float blockAllSum(float v, float* scr) {
    #pragma unroll
    for (int o = 32; o > 0; o >>= 1) v += __shfl_down(v, o, 64);
    int lane = threadIdx.x & 63, w = threadIdx.x >> 6;
    __syncthreads();
    if (lane == 0) scr[w] = v;
    __syncthreads();
    return scr[0] + scr[1] + scr[2] + scr[3];
}

// ================= K2: batchnorm1 stats — single pass, 1024 threads =================
__global__ void k_bnstats(const float* __restrict__ xm, float* __restrict__ mo,
                          float* __restrict__ ro) {
    __shared__ float scr[32];
    int j = blockIdx.x, t = threadIdx.x;
    float s = 0.f, s2 = 0.f;
    for (int b = t; b < BATCH; b += 1024) {
        float v = xm[b * NQ + j];
        s += v; s2 += v * v;
    }
    #pragma unroll
    for (int o = 32; o > 0; o >>= 1) { s += __shfl_down(s, o, 64); s2 += __shfl_down(s2, o, 64); }
    int lane = t & 63, w = t >> 6;
    if (lane == 0) { scr[w] = s; scr[16 + w] = s2; }
    __syncthreads();
    if (t == 0) {
        float S = 0.f, S2 = 0.f;
        #pragma unroll
        for (int i = 0; i < 16; i++) { S += scr[i]; S2 += scr[16 + i]; }
        float mean = S / (float)BATCH;
        float var  = S2 / (float)BATCH - mean * mean;
        mo[j] = mean;
        ro[j] = 1.f / sqrtf(var + BN_EPS);
    }
}

// ================= K3: quantum circuit — R15 body (126 us) + compact atomic moment tail ======
// Canonical amp index: qubit q at bit (11-q). Swizzle: slot = idx ^ (((idx>>5)&7)<<1).
// Window A: local bits 3..0 (qubits 8-11, b128); B: bits 7..4; C: bits 11..8.
// 3-pass layer schedule C->B->A by commutation (R14); CRY->U fusion (R15).
// Gate coeffs via SCALAR const float* loads (s_load + compiler-folded splats) — R16's
// packed v2f tables regressed 126->170 us (vector loads + vmcnt stalls). Keep scalar form.
// LESSONS (measured): R10 — no offset hoisting / waves_per_eu. R12 — no 128B-padded
// atomics. R11 — no grid-scaled redundant stats math. R16 — no v2f coefficient tables.
#define SLA2(j) ((T << 4) | ((((j) ^ ((T >> 1) & 7))) << 1))
#define SLB(m)  (((T & 0xF0) << 4) | ((m) << 4) | ((T & 15) ^ ((m) & 14)))
#define SLC(m)  (((m) << 8) | (T ^ ((((T >> 5) & 7)) << 1)))

#define LDA(j, Ra, Rb) { v4f t_ = *(const v4f*)(xch + SLA2(j));                 \
    Ra = __builtin_shufflevector(t_, t_, 0, 1);                                 \
    Rb = __builtin_shufflevector(t_, t_, 2, 3); }
#define STA(j, Ra, Rb) { v4f t_ = __builtin_shufflevector(Ra, Rb, 0, 1, 2, 3);  \
    *(v4f*)(xch + SLA2(j)) = t_; }

#define LOADA do { LDA(0,s0,s1) LDA(1,s2,s3) LDA(2,s4,s5) LDA(3,s6,s7)          \
    LDA(4,s8,s9) LDA(5,s10,s11) LDA(6,s12,s13) LDA(7,s14,s15) } while (0)
#define STORA do { STA(0,s0,s1) STA(1,s2,s3) STA(2,s4,s5) STA(3,s6,s7)          \
    STA(4,s8,s9) STA(5,s10,s11) STA(6,s12,s13) STA(7,s14,s15) } while (0)

#define LOADW(SL) do {                                                          \
    s0=xch[SL(0)];  s1=xch[SL(1)];  s2=xch[SL(2)];  s3=xch[SL(3)];              \
    s4=xch[SL(4)];  s5=xch[SL(5)];  s6=xch[SL(6)];  s7=xch[SL(7)];              \
    s8=xch[SL(8)];  s9=xch[SL(9)];  s10=xch[SL(10)]; s11=xch[SL(11)];           \
    s12=xch[SL(12)]; s13=xch[SL(13)]; s14=xch[SL(14)]; s15=xch[SL(15)]; } while (0)
#define STORW(SL) do {                                                          \
    xch[SL(0)]=s0;  xch[SL(1)]=s1;  xch[SL(2)]=s2;  xch[SL(3)]=s3;              \
    xch[SL(4)]=s4;  xch[SL(5)]=s5;  xch[SL(6)]=s6;  xch[SL(7)]=s7;              \
    xch[SL(8)]=s8;  xch[SL(9)]=s9;  xch[SL(10)]=s10; xch[SL(11)]=s11;           \
    xch[SL(12)]=s12; xch[SL(13)]=s13; xch[SL(14)]=s14; xch[SL(15)]=s15; } while (0)

#define U_LOADP(uptr) const float* u_ = (uptr);                                  \
    v2f c00r = {u_[0], u_[0]}, c00i = {-u_[1], u_[1]};                           \
    v2f c01r = {u_[2], u_[2]}, c01i = {-u_[3], u_[3]};                           \
    v2f c10r = {u_[4], u_[4]}, c10i = {-u_[5], u_[5]};                           \
    v2f c11r = {u_[6], u_[6]}, c11i = {-u_[7], u_[7]};

#define U_LOADF(uptr) const float* f_ = (uptr);                                  \
    v2f d00r = {f_[0], f_[0]}, d00i = {-f_[1], f_[1]};                           \
    v2f d01r = {f_[2], f_[2]}, d01i = {-f_[3], f_[3]};                           \
    v2f d10r = {f_[4], f_[4]}, d10i = {-f_[5], f_[5]};                           \
    v2f d11r = {f_[6], f_[6]}, d11i = {-f_[7], f_[7]};

#define U_PAIRP(A, B) { v2f a0 = A, a1 = B, a0s = SW2(a0), a1s = SW2(a1);        \
    A = a0*c00r + a0s*c00i + a1*c01r + a1s*c01i;                                 \
    B = a0*c10r + a0s*c10i + a1*c11r + a1s*c11i; }

#define U_PAIRF(A, B) { v2f a0 = A, a1 = B, a0s = SW2(a0), a1s = SW2(a1);        \
    A = a0*d00r + a0s*d00i + a1*d01r + a1s*d01i;                                 \
    B = a0*d10r + a0s*d10i + a1*d11r + a1s*d11i; }

#define APPLY_U_K3(uptr) do { U_LOADP(uptr)                                      \
    U_PAIRP(s0,s8) U_PAIRP(s1,s9) U_PAIRP(s2,s10) U_PAIRP(s3,s11)                \
    U_PAIRP(s4,s12) U_PAIRP(s5,s13) U_PAIRP(s6,s14) U_PAIRP(s7,s15) } while (0)

// fused: gate on bit2, coeff set selected by pair's bit3
#define APPLY_UF_K2(uP, uF) do { U_LOADP(uP) U_LOADF(uF)                         \
    U_PAIRP(s0,s4) U_PAIRP(s1,s5) U_PAIRP(s2,s6) U_PAIRP(s3,s7)                  \
    U_PAIRF(s8,s12) U_PAIRF(s9,s13) U_PAIRF(s10,s14) U_PAIRF(s11,s15) } while (0)
// fused: gate on bit1, selected by bit2
#define APPLY_UF_K1(uP, uF) do { U_LOADP(uP) U_LOADF(uF)                         \
    U_PAIRP(s0,s2) U_PAIRP(s1,s3) U_PAIRF(s4,s6) U_PAIRF(s5,s7)                  \
    U_PAIRP(s8,s10) U_PAIRP(s9,s11) U_PAIRF(s12,s14) U_PAIRF(s13,s15) } while (0)
// fused: gate on bit0, selected by bit1
#define APPLY_UF_K0(uP, uF) do { U_LOADP(uP) U_LOADF(uF)                         \
    U_PAIRP(s0,s1) U_PAIRF(s2,s3) U_PAIRP(s4,s5) U_PAIRF(s6,s7)                  \
    U_PAIRP(s8,s9) U_PAIRF(s10,s11) U_PAIRP(s12,s13) U_PAIRF(s14,s15) } while (0)

#define RY_PAIRP(A, B) { v2f a0 = A, a1 = B;                                     \
    A = a0*cc2 - a1*ss2;  B = a0*ss2 + a1*cc2; }

#define RYALL_K3(cc, ss) do { v2f cc2 = {(cc),(cc)}, ss2 = {(ss),(ss)};          \
    RY_PAIRP(s0,s8) RY_PAIRP(s1,s9) RY_PAIRP(s2,s10) RY_PAIRP(s3,s11)            \
    RY_PAIRP(s4,s12) RY_PAIRP(s5,s13) RY_PAIRP(s6,s14) RY_PAIRP(s7,s15) } while (0)

// init in window C order: idx = m<<8 | T; qubits 0-3 from m bits 3..0
#define INITJC(SR, j) { SR.x = f * (((j)&8)?qs0:qc0) * (((j)&4)?qs1:qc1)         \
    * (((j)&2)?qs2:qc2) * (((j)&1)?qs3:qc3); SR.y = 0.f; }
#define PRJ(S) ((S).x*(S).x + (S).y*(S).y)
#define WREDUCE(v) { v += __shfl_down(v,32,64); v += __shfl_down(v,16,64);       \
    v += __shfl_down(v,8,64); v += __shfl_down(v,4,64);                          \
    v += __shfl_down(v,2,64); v += __shfl_down(v,1,64); }

#define MKQ(i) float qc##i, qs##i; {                                             \
    float h_ = h##i;                                                             \
    float a_ = nz ? h_ * rinv : h_;                                              \
    float amp_ = fminf(fabsf(a_), 1.f);                                          \
    qc##i = sqrtf(fmaxf(1.f - amp_ * amp_, 0.f));                                \
    qs##i = (a_ < 0.f) ? -amp_ : amp_; }

__launch_bounds__(256)
__global__ void k_quantum(const float* __restrict__ enc,
                          const float* __restrict__ bn1m, const float* __restrict__ bn1r,
                          const float* __restrict__ g1, const float* __restrict__ b1,
                          const float* __restrict__ gU, const float* __restrict__ gC,
                          const float* __restrict__ gF,
                          float* __restrict__ probs, float* __restrict__ acc90) {
    __shared__ __align__(16) v2f xch[NST];                        // exactly 32 KB

    int T = threadIdx.x, b = blockIdx.x;

    // ---- BN1 + tanh + qv, all uniform scalars computed in registers ----
    const float* er = enc + b * NQ;
    float h0  = tanhf(g1[0]  * (er[0]  - bn1m[0])  * bn1r[0]  + b1[0]);
    float h1  = tanhf(g1[1]  * (er[1]  - bn1m[1])  * bn1r[1]  + b1[1]);
    float h2  = tanhf(g1[2]  * (er[2]  - bn1m[2])  * bn1r[2]  + b1[2]);
    float h3  = tanhf(g1[3]  * (er[3]  - bn1m[3])  * bn1r[3]  + b1[3]);
    float h4  = tanhf(g1[4]  * (er[4]  - bn1m[4])  * bn1r[4]  + b1[4]);
    float h5  = tanhf(g1[5]  * (er[5]  - bn1m[5])  * bn1r[5]  + b1[5]);
    float h6  = tanhf(g1[6]  * (er[6]  - bn1m[6])  * bn1r[6]  + b1[6]);
    float h7  = tanhf(g1[7]  * (er[7]  - bn1m[7])  * bn1r[7]  + b1[7]);
    float h8  = tanhf(g1[8]  * (er[8]  - bn1m[8])  * bn1r[8]  + b1[8]);
    float h9  = tanhf(g1[9]  * (er[9]  - bn1m[9])  * bn1r[9]  + b1[9]);
    float h10 = tanhf(g1[10] * (er[10] - bn1m[10]) * bn1r[10] + b1[10]);
    float h11 = tanhf(g1[11] * (er[11] - bn1m[11]) * bn1r[11] + b1[11]);
    float n2 = h0*h0+h1*h1+h2*h2+h3*h3+h4*h4+h5*h5+h6*h6+h7*h7
             + h8*h8+h9*h9+h10*h10+h11*h11;
    float norm = sqrtf(n2);
    bool  nz   = norm > 0.f;
    float rinv = 1.f / fmaxf(norm, 1e-30f);
    MKQ(0) MKQ(1) MKQ(2) MKQ(3) MKQ(4) MKQ(5) MKQ(6) MKQ(7)
    MKQ(8) MKQ(9) MKQ(10) MKQ(11)

    v2f s0, s1, s2, s3, s4, s5, s6, s7, s8, s9, s10, s11, s12, s13, s14, s15;

    // ---- pass C, layer 0: init + U0 + fused(U1,CRY0) + fused(U2,CRY1) + fused(U3,CRY2) ----
    {
        float f = ((T>>7)&1 ? qs4 : qc4) * ((T>>6)&1 ? qs5 : qc5)
                * ((T>>5)&1 ? qs6 : qc6) * ((T>>4)&1 ? qs7 : qc7)
                * ((T>>3)&1 ? qs8 : qc8) * ((T>>2)&1 ? qs9 : qc9)
                * ((T>>1)&1 ? qs10 : qc10) * ((T>>0)&1 ? qs11 : qc11);
        INITJC(s0,0)  INITJC(s1,1)  INITJC(s2,2)  INITJC(s3,3)
        INITJC(s4,4)  INITJC(s5,5)  INITJC(s6,6)  INITJC(s7,7)
        INITJC(s8,8)  INITJC(s9,9)  INITJC(s10,10) INITJC(s11,11)
        INITJC(s12,12) INITJC(s13,13) INITJC(s14,14) INITJC(s15,15)
        APPLY_U_K3(gU + 0 * 8);
        APPLY_UF_K2(gU + 1 * 8, gF + 0 * 8);
        APPLY_UF_K1(gU + 2 * 8, gF + 1 * 8);
        APPLY_UF_K0(gU + 3 * 8, gF + 2 * 8);
        STORW(SLC);
    }
    __syncthreads();                          // C->B crosses waves

    #pragma unroll 1
    for (int l = 0; l < DEPTH; l++) {
        const float* UL = gU + l * 96;
        const float* CL = gC + l * 22;
        const float* FL = gF + l * 72;
        // ---- window B: U4 + CRY3(pred) + fused(U5,CRY4) + fused(U6,CRY5) + fused(U7,CRY6) ----
        LOADW(SLB);
        APPLY_U_K3(UL + 4 * 8);
        if (T & 16) RYALL_K3(CL[6], CL[7]);   // CRY3 (ctrl = idx bit 8)
        APPLY_UF_K2(UL + 5 * 8, FL + 3 * 8);
        APPLY_UF_K1(UL + 6 * 8, FL + 4 * 8);
        APPLY_UF_K0(UL + 7 * 8, FL + 5 * 8);
        STORW(SLB);
        __builtin_amdgcn_wave_barrier();      // B->A is wave-private
        // ---- window A: U8 + CRY7(pred) + fused(U9,CRY8) + fused(U10,CRY9) + fused(U11,CRY10) ----
        LOADA;
        APPLY_U_K3(UL + 8 * 8);
        if (T & 1) RYALL_K3(CL[14], CL[15]);  // CRY7 (ctrl = idx bit 4)
        APPLY_UF_K2(UL + 9 * 8, FL + 6 * 8);
        APPLY_UF_K1(UL + 10 * 8, FL + 7 * 8);
        APPLY_UF_K0(UL + 11 * 8, FL + 8 * 8);
        if (l < DEPTH - 1) {
            STORA;
            __syncthreads();                  // A->C crosses waves
            // ---- window C, layer l+1: U0 + fused CRY0-2 ----
            const float* UN = gU + (l + 1) * 96;
            const float* FN = gF + (l + 1) * 72;
            LOADW(SLC);
            APPLY_U_K3(UN + 0 * 8);
            APPLY_UF_K2(UN + 1 * 8, FN + 0 * 8);
            APPLY_UF_K1(UN + 2 * 8, FN + 1 * 8);
            APPLY_UF_K0(UN + 3 * 8, FN + 2 * 8);
            STORW(SLC);
            __syncthreads();                  // C->B crosses waves
        }
    }

    // ---- marginals from registers (window A: idx = T<<4 | m) ----
    float p0 = PRJ(s0),  p1 = PRJ(s1),  p2 = PRJ(s2),  p3 = PRJ(s3);
    float p4 = PRJ(s4),  p5 = PRJ(s5),  p6 = PRJ(s6),  p7 = PRJ(s7);
    float p8 = PRJ(s8),  p9 = PRJ(s9),  p10 = PRJ(s10), p11 = PRJ(s11);
    float p12 = PRJ(s12), p13 = PRJ(s13), p14 = PRJ(s14), p15 = PRJ(s15);
    float tot = p0+p1+p2+p3+p4+p5+p6+p7+p8+p9+p10+p11+p12+p13+p14+p15;
    float r8  = p8+p9+p10+p11+p12+p13+p14+p15;
    float r9  = p4+p5+p6+p7+p12+p13+p14+p15;
    float r10 = p2+p3+p6+p7+p10+p11+p14+p15;
    float r11 = p1+p3+p5+p7+p9+p11+p13+p15;
    float r0 = (T & 128) ? tot : 0.f;
    float r1 = (T & 64)  ? tot : 0.f;
    float r2 = (T & 32)  ? tot : 0.f;
    float r3 = (T & 16)  ? tot : 0.f;
    float r4 = (T & 8)   ? tot : 0.f;
    float r5 = (T & 4)   ? tot : 0.f;
    float r6 = (T & 2)   ? tot : 0.f;
    float r7 = (T & 1)   ? tot : 0.f;

    WREDUCE(r0) WREDUCE(r1) WREDUCE(r2) WREDUCE(r3) WREDUCE(r4) WREDUCE(r5)
    WREDUCE(r6) WREDUCE(r7) WREDUCE(r8) WREDUCE(r9) WREDUCE(r10) WREDUCE(r11)

    __syncthreads();                     // xch no longer needed as state
    float* red = (float*)xch;
    int lane = T & 63, w = T >> 6;
    if (lane == 0) {
        float* rr = red + w * NQ;
        rr[0]=r0; rr[1]=r1; rr[2]=r2; rr[3]=r3; rr[4]=r4; rr[5]=r5;
        rr[6]=r6; rr[7]=r7; rr[8]=r8; rr[9]=r9; rr[10]=r10; rr[11]=r11;
    }
    __syncthreads();
    float* pq = red + 64;
    if (T < NQ) {
        float v = red[T] + red[NQ + T] + red[2 * NQ + T] + red[3 * NQ + T];
        probs[b * NQ + T] = v;
        pq[T] = v;
    }
    __syncthreads();
    // ---- moment accumulation: 12 sums + 78 pair products (q <= q2), compact ----
    if (T < 90) {
        float v;
        if (T < NQ) {
            v = pq[T];
        } else {
            int j = T - NQ, q = 0;
            while (j >= NQ - q) { j -= NQ - q; q++; }
            v = pq[q] * pq[q + j];
        }
        unsafeAtomicAdd(acc90 + T, v);
    }
}

// ================= K4: pmean/cov/rstd from moments (one block) =================
__global__ void k_rstd(const float* __restrict__ acc90, const float* __restrict__ dw,
                       float* __restrict__ pmean, float* __restrict__ rstd) {
    __shared__ float pm[NQ];
    __shared__ float cv[NQ * NQ];
    int t = threadIdx.x;
    if (t < NQ) {
        float m = acc90[t] * INV_B;
        pm[t] = m;
        pmean[t] = m;
    }
    __syncthreads();
    if (t < NQ * NQ) {
        int q = t / NQ, q2 = t - q * NQ;
        int lo = q < q2 ? q : q2, hi = q < q2 ? q2 : q;
        float P = acc90[NQ + lo * NQ - (lo * (lo - 1)) / 2 + (hi - lo)];
        cv[t] = P * INV_B - pm[q] * pm[q2];
    }
    __syncthreads();
    float w[NQ];
    #pragma unroll
    for (int q = 0; q < NQ; q++) w[q] = dw[t * NQ + q];
    float var = 0.f;
    #pragma unroll
    for (int q = 0; q < NQ; q++) {
        float a = 0.f;
        #pragma unroll
        for (int q2 = 0; q2 < NQ; q2++) a += cv[q * NQ + q2] * w[q2];
        var += w[q] * a;
    }
    rstd[t] = 1.f / sqrtf(var + BN_EPS);
}

// ================= K5: final decode + BN2 (2 rows per block) =================
__global__ void k_final(const float* __restrict__ probs, const float* __restrict__ pmean,
                        const float* __restrict__ rstd, const float* __restrict__ dw,
                        const float* __restrict__ g2, const float* __restrict__ b2,
                        float* __restrict__ out) {
    __shared__ float cp[2][NQ];
    int b0 = blockIdx.x * 2;
    int t = threadIdx.x;
    int half = t >> 8, j = t & 255;
    if (t < NQ)                      cp[0][t]       = probs[b0 * NQ + t]        - pmean[t];
    else if (t >= 256 && t < 256+NQ) cp[1][t - 256] = probs[(b0+1) * NQ + t-256] - pmean[t - 256];
    __syncthreads();
    float acc = 0.f;
    #pragma unroll
    for (int q = 0; q < NQ; q++) acc += cp[half][q] * dw[j * NQ + q];
    out[(b0 + half) * OUT_SZ + j] = acc * rstd[j] * g2[j] + b2[j];
}

extern "C" void kernel_launch(void* const* d_in, const int* in_sizes, int n_in,
                              void* d_out, int out_size, void* d_ws, size_t ws_size,
                              hipStream_t stream) {
    const float* x     = (const float*)d_in[0];
    const float* enc_w = (const float*)d_in[1];
    const float* enc_b = (const float*)d_in[2];
    const float* rot   = (const float*)d_in[3];
    const float* ent   = (const float*)d_in[4];
    const float* dec_w = (const float*)d_in[5];
    // d_in[6] = dec_b — cancels inside BN2
    const float* g1    = (const float*)d_in[7];
    const float* b1    = (const float*)d_in[8];
    const float* g2    = (const float*)d_in[9];
    const float* b2    = (const float*)d_in[10];

    float* ws    = (float*)d_ws;
    float* enc   = ws + OFF_ENC;
    float* bn1m  = ws + OFF_BN1M;
    float* bn1r  = ws + OFF_BN1R;
    float* gU    = ws + OFF_GU;
    float* gC    = ws + OFF_GC;
    float* gF    = ws + OFF_GF;
    float* prb   = ws + OFF_PROBS;
    float* acc90 = ws + OFF_ACC90;
    float* rstd  = ws + OFF_RSTD;
    float* pmean = ws + OFF_PMEAN;

    hipLaunchKernelGGL(k_encode, dim3(1025), dim3(256), 0, stream,
                       x, enc_w, enc_b, rot, ent, enc, gU, gC, gF, acc90);
    hipLaunchKernelGGL(k_bnstats, dim3(NQ), dim3(1024), 0, stream, enc, bn1m, bn1r);
    hipLaunchKernelGGL(k_quantum, dim3(BATCH), dim3(256), 0, stream,
                       enc, bn1m, bn1r, g1, b1, gU, gC, gF, prb, acc90);
    hipLaunchKernelGGL(k_rstd, dim3(1), dim3(OUT_SZ), 0, stream,
                       acc90, dec_w, pmean, rstd);
    hipLaunchKernelGGL(k_final, dim3(BATCH / 2), dim3(512), 0, stream,
                       prb, pmean, rstd, dec_w, g2, b2, (float*)d_out);
}

// Round 18
// 206.887 us; speedup vs baseline: 1.0622x; 1.0422x over previous
//
#include <hip/hip_runtime.h>

#define BATCH   4096
#define IN_SZ   512
#define NQ      12
#define OUT_SZ  256
#define DEPTH   3
#define NST     4096   // 2^NQ
#define BN_EPS  1e-5f

// ---- ws layout (in floats) ----
#define OFF_ENC    0            // 4096*12 = 49152
#define OFF_BN1M   49152
#define OFF_BN1R   49168
#define OFF_GU     49184        // 288
#define OFF_GC     49472        // 66 (pad 96)
#define OFF_GF     49568        // DEPTH*9*8 = 216 (pad 224): fused Ry*U products
#define OFF_PROBS  49792        // 49152
#define OFF_PMEAN  98944
#define OFF_COV    98960        // 144
#define OFF_RSTD   99104        // 256

typedef float v2f __attribute__((ext_vector_type(2)));
typedef float v4f __attribute__((ext_vector_type(4)));
#define SW2(a) __builtin_shufflevector(a, a, 1, 0)

// ================= K1: encode, wave-per-row (+ gates & fused products in block 1024) =========
__global__ void k_encode(const float* __restrict__ x, const float* __restrict__ w,
                         const float* __restrict__ bvec,
                         const float* __restrict__ rot, const float* __restrict__ ent,
                         float* __restrict__ enc, float* __restrict__ gU, float* __restrict__ gC,
                         float* __restrict__ gF) {
    if (blockIdx.x == 1024) {
        int t = threadIdx.x;
        if (t < DEPTH * NQ) {
            float ax = rot[t * 3 + 0] * 0.5f;
            float ay = rot[t * 3 + 1] * 0.5f;
            float az = rot[t * 3 + 2] * 0.5f;
            float cx = cosf(ax), sx = sinf(ax);
            float cy = cosf(ay), sy = sinf(ay);
            float cz = cosf(az), sz = sinf(az);
            float m00r =  cy * cx, m00i =  sy * sx;
            float m01r = -sy * cx, m01i = -cy * sx;
            float m10r =  sy * cx, m10i = -cy * sx;
            float m11r =  cy * cx, m11i = -sy * sx;
            float* o = gU + t * 8;
            o[0] = cz * m00r + sz * m00i;  o[1] = cz * m00i - sz * m00r;
            o[2] = cz * m01r + sz * m01i;  o[3] = cz * m01i - sz * m01r;
            o[4] = cz * m10r - sz * m10i;  o[5] = cz * m10i + sz * m10r;
            o[6] = cz * m11r - sz * m11i;  o[7] = cz * m11i + sz * m11r;
        }
        if (t >= 64 && t - 64 < DEPTH * (NQ - 1)) {
            int i = t - 64;
            float th = ent[i] * 0.5f;
            gC[i * 2 + 0] = cosf(th);
            gC[i * 2 + 1] = sinf(th);
        }
        // fused products P = Ry(theta_c) * U_{c+1} for c in {0,1,2, 4,5,6, 8,9,10}
        if (t >= 128 && t - 128 < DEPTH * 9) {
            int i = t - 128;              // 0..26
            int l = i / 9, k = i % 9;
            int c = k + k / 3;            // 0,1,2,4,5,6,8,9,10
            int tq = c + 1;
            const float* rr = rot + (l * NQ + tq) * 3;
            float ax = rr[0] * 0.5f, ay = rr[1] * 0.5f, az = rr[2] * 0.5f;
            float cx = cosf(ax), sx = sinf(ax);
            float cy = cosf(ay), sy = sinf(ay);
            float cz = cosf(az), sz = sinf(az);
            float m00r =  cy * cx, m00i =  sy * sx;
            float m01r = -sy * cx, m01i = -cy * sx;
            float m10r =  sy * cx, m10i = -cy * sx;
            float m11r =  cy * cx, m11i = -sy * sx;
            float u0 = cz * m00r + sz * m00i, u1 = cz * m00i - sz * m00r;
            float u2 = cz * m01r + sz * m01i, u3 = cz * m01i - sz * m01r;
            float u4 = cz * m10r - sz * m10i, u5 = cz * m10i + sz * m10r;
            float u6 = cz * m11r - sz * m11i, u7 = cz * m11i + sz * m11r;
            float th = ent[l * (NQ - 1) + c] * 0.5f;
            float c_ = cosf(th), s_ = sinf(th);
            float* o = gF + i * 8;
            o[0] = c_ * u0 - s_ * u4;  o[1] = c_ * u1 - s_ * u5;
            o[2] = c_ * u2 - s_ * u6;  o[3] = c_ * u3 - s_ * u7;
            o[4] = s_ * u0 + c_ * u4;  o[5] = s_ * u1 + c_ * u5;
            o[6] = s_ * u2 + c_ * u6;  o[7] = s_ * u3 + c_ * u7;
        }
        return;
    }
    int t = threadIdx.x;
    int wv = t >> 6, lane = t & 63;
    int row = blockIdx.x * 4 + wv;              // 1024 blocks x 4 waves = 4096 rows
    const float4* xr = (const float4*)(x + row * IN_SZ) + lane * 2;
    float4 xa = xr[0], xb = xr[1];
    float acc[NQ];
    #pragma unroll
    for (int q = 0; q < NQ; q++) {
        const float4* wr = (const float4*)(w + q * IN_SZ) + lane * 2;
        float4 wa = wr[0], wb = wr[1];
        float d = xa.x*wa.x + xa.y*wa.y + xa.z*wa.z + xa.w*wa.w
                + xb.x*wb.x + xb.y*wb.y + xb.z*wb.z + xb.w*wb.w;
        #pragma unroll
        for (int o = 32; o > 0; o >>= 1) d += __shfl_down(d, o, 64);
        acc[q] = d;
    }
    if (lane == 0) {
        float* er = enc + row * NQ;
        #pragma unroll
        for (int q = 0; q < NQ; q++) er[q] = acc[q] + bvec[q];
    }
}

// ---------------- block-wide sum for 256-thread blocks (broadcast) ----------------
__device__ float blockAllSum(float v, float* scr) {
    #pragma unroll
    for (int o = 32; o > 0; o >>= 1) v += __shfl_down(v, o, 64);
    int lane = threadIdx.x & 63, w = threadIdx.x >> 6;
    __syncthreads();
    if (lane == 0) scr[w] = v;
    __syncthreads();
    return scr[0] + scr[1] + scr[2] + scr[3];
}

// ================= K2: batchnorm1 stats — single pass, 1024 threads =================
__global__ void k_bnstats(const float* __restrict__ xm, float* __restrict__ mo,
                          float* __restrict__ ro) {
    __shared__ float scr[32];
    int j = blockIdx.x, t = threadIdx.x;
    float s = 0.f, s2 = 0.f;
    for (int b = t; b < BATCH; b += 1024) {
        float v = xm[b * NQ + j];
        s += v; s2 += v * v;
    }
    #pragma unroll
    for (int o = 32; o > 0; o >>= 1) { s += __shfl_down(s, o, 64); s2 += __shfl_down(s2, o, 64); }
    int lane = t & 63, w = t >> 6;
    if (lane == 0) { scr[w] = s; scr[16 + w] = s2; }
    __syncthreads();
    if (t == 0) {
        float S = 0.f, S2 = 0.f;
        #pragma unroll
        for (int i = 0; i < 16; i++) { S += scr[i]; S2 += scr[16 + i]; }
        float mean = S / (float)BATCH;
        float var  = S2 / (float)BATCH - mean * mean;
        mo[j] = mean;
        ro[j] = 1.f / sqrtf(var + BN_EPS);
    }
}

// ================= K3: quantum circuit — 3-pass schedule + CRY->U fusion (R15, 126 us) =======
// Canonical amp index: qubit q at bit (11-q). Swizzle: slot = idx ^ (((idx>>5)&7)<<1).
// Window A: local bits 3..0 (qubits 8-11, b128); B: bits 7..4; C: bits 11..8.
// 3-pass layer schedule C->B->A by commutation (R14); CRY->U fusion (R15).
// Gate coeffs via SCALAR const float* loads (s_load + compiler-folded splats).
// LESSONS (measured): R10 — no offset hoisting / waves_per_eu (146->163).
// R12 — no 128B-padded atomics. R11 — no grid-scaled redundant stats math.
// R16 — no v2f coefficient tables (vector loads + vmcnt stalls, 126->170).
// R17 — no atomic moment tail (+11 us on k_quantum > one launch saved).
#define SLA2(j) ((T << 4) | ((((j) ^ ((T >> 1) & 7))) << 1))
#define SLB(m)  (((T & 0xF0) << 4) | ((m) << 4) | ((T & 15) ^ ((m) & 14)))
#define SLC(m)  (((m) << 8) | (T ^ ((((T >> 5) & 7)) << 1)))

#define LDA(j, Ra, Rb) { v4f t_ = *(const v4f*)(xch + SLA2(j));                 \
    Ra = __builtin_shufflevector(t_, t_, 0, 1);                                 \
    Rb = __builtin_shufflevector(t_, t_, 2, 3); }
#define STA(j, Ra, Rb) { v4f t_ = __builtin_shufflevector(Ra, Rb, 0, 1, 2, 3);  \
    *(v4f*)(xch + SLA2(j)) = t_; }

#define LOADA do { LDA(0,s0,s1) LDA(1,s2,s3) LDA(2,s4,s5) LDA(3,s6,s7)          \
    LDA(4,s8,s9) LDA(5,s10,s11) LDA(6,s12,s13) LDA(7,s14,s15) } while (0)
#define STORA do { STA(0,s0,s1) STA(1,s2,s3) STA(2,s4,s5) STA(3,s6,s7)          \
    STA(4,s8,s9) STA(5,s10,s11) STA(6,s12,s13) STA(7,s14,s15) } while (0)

#define LOADW(SL) do {                                                          \
    s0=xch[SL(0)];  s1=xch[SL(1)];  s2=xch[SL(2)];  s3=xch[SL(3)];              \
    s4=xch[SL(4)];  s5=xch[SL(5)];  s6=xch[SL(6)];  s7=xch[SL(7)];              \
    s8=xch[SL(8)];  s9=xch[SL(9)];  s10=xch[SL(10)]; s11=xch[SL(11)];           \
    s12=xch[SL(12)]; s13=xch[SL(13)]; s14=xch[SL(14)]; s15=xch[SL(15)]; } while (0)
#define STORW(SL) do {                                                          \
    xch[SL(0)]=s0;  xch[SL(1)]=s1;  xch[SL(2)]=s2;  xch[SL(3)]=s3;              \
    xch[SL(4)]=s4;  xch[SL(5)]=s5;  xch[SL(6)]=s6;  xch[SL(7)]=s7;              \
    xch[SL(8)]=s8;  xch[SL(9)]=s9;  xch[SL(10)]=s10; xch[SL(11)]=s11;           \
    xch[SL(12)]=s12; xch[SL(13)]=s13; xch[SL(14)]=s14; xch[SL(15)]=s15; } while (0)

#define U_LOADP(uptr) const float* u_ = (uptr);                                  \
    v2f c00r = {u_[0], u_[0]}, c00i = {-u_[1], u_[1]};                           \
    v2f c01r = {u_[2], u_[2]}, c01i = {-u_[3], u_[3]};                           \
    v2f c10r = {u_[4], u_[4]}, c10i = {-u_[5], u_[5]};                           \
    v2f c11r = {u_[6], u_[6]}, c11i = {-u_[7], u_[7]};

#define U_LOADF(uptr) const float* f_ = (uptr);                                  \
    v2f d00r = {f_[0], f_[0]}, d00i = {-f_[1], f_[1]};                           \
    v2f d01r = {f_[2], f_[2]}, d01i = {-f_[3], f_[3]};                           \
    v2f d10r = {f_[4], f_[4]}, d10i = {-f_[5], f_[5]};                           \
    v2f d11r = {f_[6], f_[6]}, d11i = {-f_[7], f_[7]};

#define U_PAIRP(A, B) { v2f a0 = A, a1 = B, a0s = SW2(a0), a1s = SW2(a1);        \
    A = a0*c00r + a0s*c00i + a1*c01r + a1s*c01i;                                 \
    B = a0*c10r + a0s*c10i + a1*c11r + a1s*c11i; }

#define U_PAIRF(A, B) { v2f a0 = A, a1 = B, a0s = SW2(a0), a1s = SW2(a1);        \
    A = a0*d00r + a0s*d00i + a1*d01r + a1s*d01i;                                 \
    B = a0*d10r + a0s*d10i + a1*d11r + a1s*d11i; }

#define APPLY_U_K3(uptr) do { U_LOADP(uptr)                                      \
    U_PAIRP(s0,s8) U_PAIRP(s1,s9) U_PAIRP(s2,s10) U_PAIRP(s3,s11)                \
    U_PAIRP(s4,s12) U_PAIRP(s5,s13) U_PAIRP(s6,s14) U_PAIRP(s7,s15) } while (0)

// fused: gate on bit2, coeff set selected by pair's bit3
#define APPLY_UF_K2(uP, uF) do { U_LOADP(uP) U_LOADF(uF)                         \
    U_PAIRP(s0,s4) U_PAIRP(s1,s5) U_PAIRP(s2,s6) U_PAIRP(s3,s7)                  \
    U_PAIRF(s8,s12) U_PAIRF(s9,s13) U_PAIRF(s10,s14) U_PAIRF(s11,s15) } while (0)
// fused: gate on bit1, selected by bit2
#define APPLY_UF_K1(uP, uF) do { U_LOADP(uP) U_LOADF(uF)                         \
    U_PAIRP(s0,s2) U_PAIRP(s1,s3) U_PAIRF(s4,s6) U_PAIRF(s5,s7)                  \
    U_PAIRP(s8,s10) U_PAIRP(s9,s11) U_PAIRF(s12,s14) U_PAIRF(s13,s15) } while (0)
// fused: gate on bit0, selected by bit1
#define APPLY_UF_K0(uP, uF) do { U_LOADP(uP) U_LOADF(uF)                         \
    U_PAIRP(s0,s1) U_PAIRF(s2,s3) U_PAIRP(s4,s5) U_PAIRF(s6,s7)                  \
    U_PAIRP(s8,s9) U_PAIRF(s10,s11) U_PAIRP(s12,s13) U_PAIRF(s14,s15) } while (0)

#define RY_PAIRP(A, B) { v2f a0 = A, a1 = B;                                     \
    A = a0*cc2 - a1*ss2;  B = a0*ss2 + a1*cc2; }

#define RYALL_K3(cc, ss) do { v2f cc2 = {(cc),(cc)}, ss2 = {(ss),(ss)};          \
    RY_PAIRP(s0,s8) RY_PAIRP(s1,s9) RY_PAIRP(s2,s10) RY_PAIRP(s3,s11)            \
    RY_PAIRP(s4,s12) RY_PAIRP(s5,s13) RY_PAIRP(s6,s14) RY_PAIRP(s7,s15) } while (0)

// init in window C order: idx = m<<8 | T; qubits 0-3 from m bits 3..0
#define INITJC(SR, j) { SR.x = f * (((j)&8)?qs0:qc0) * (((j)&4)?qs1:qc1)         \
    * (((j)&2)?qs2:qc2) * (((j)&1)?qs3:qc3); SR.y = 0.f; }
#define PRJ(S) ((S).x*(S).x + (S).y*(S).y)
#define WREDUCE(v) { v += __shfl_down(v,32,64); v += __shfl_down(v,16,64);       \
    v += __shfl_down(v,8,64); v += __shfl_down(v,4,64);                          \
    v += __shfl_down(v,2,64); v += __shfl_down(v,1,64); }

#define MKQ(i) float qc##i, qs##i; {                                             \
    float h_ = h##i;                                                             \
    float a_ = nz ? h_ * rinv : h_;                                              \
    float amp_ = fminf(fabsf(a_), 1.f);                                          \
    qc##i = sqrtf(fmaxf(1.f - amp_ * amp_, 0.f));                                \
    qs##i = (a_ < 0.f) ? -amp_ : amp_; }

__launch_bounds__(256)
__global__ void k_quantum(const float* __restrict__ enc,
                          const float* __restrict__ bn1m, const float* __restrict__ bn1r,
                          const float* __restrict__ g1, const float* __restrict__ b1,
                          const float* __restrict__ gU, const float* __restrict__ gC,
                          const float* __restrict__ gF,
                          float* __restrict__ probs) {
    __shared__ __align__(16) v2f xch[NST];                        // exactly 32 KB

    int T = threadIdx.x, b = blockIdx.x;

    // ---- BN1 + tanh + qv, all uniform scalars computed in registers ----
    const float* er = enc + b * NQ;
    float h0  = tanhf(g1[0]  * (er[0]  - bn1m[0])  * bn1r[0]  + b1[0]);
    float h1  = tanhf(g1[1]  * (er[1]  - bn1m[1])  * bn1r[1]  + b1[1]);
    float h2  = tanhf(g1[2]  * (er[2]  - bn1m[2])  * bn1r[2]  + b1[2]);
    float h3  = tanhf(g1[3]  * (er[3]  - bn1m[3])  * bn1r[3]  + b1[3]);
    float h4  = tanhf(g1[4]  * (er[4]  - bn1m[4])  * bn1r[4]  + b1[4]);
    float h5  = tanhf(g1[5]  * (er[5]  - bn1m[5])  * bn1r[5]  + b1[5]);
    float h6  = tanhf(g1[6]  * (er[6]  - bn1m[6])  * bn1r[6]  + b1[6]);
    float h7  = tanhf(g1[7]  * (er[7]  - bn1m[7])  * bn1r[7]  + b1[7]);
    float h8  = tanhf(g1[8]  * (er[8]  - bn1m[8])  * bn1r[8]  + b1[8]);
    float h9  = tanhf(g1[9]  * (er[9]  - bn1m[9])  * bn1r[9]  + b1[9]);
    float h10 = tanhf(g1[10] * (er[10] - bn1m[10]) * bn1r[10] + b1[10]);
    float h11 = tanhf(g1[11] * (er[11] - bn1m[11]) * bn1r[11] + b1[11]);
    float n2 = h0*h0+h1*h1+h2*h2+h3*h3+h4*h4+h5*h5+h6*h6+h7*h7
             + h8*h8+h9*h9+h10*h10+h11*h11;
    float norm = sqrtf(n2);
    bool  nz   = norm > 0.f;
    float rinv = 1.f / fmaxf(norm, 1e-30f);
    MKQ(0) MKQ(1) MKQ(2) MKQ(3) MKQ(4) MKQ(5) MKQ(6) MKQ(7)
    MKQ(8) MKQ(9) MKQ(10) MKQ(11)

    v2f s0, s1, s2, s3, s4, s5, s6, s7, s8, s9, s10, s11, s12, s13, s14, s15;

    // ---- pass C, layer 0: init + U0 + fused(U1,CRY0) + fused(U2,CRY1) + fused(U3,CRY2) ----
    {
        float f = ((T>>7)&1 ? qs4 : qc4) * ((T>>6)&1 ? qs5 : qc5)
                * ((T>>5)&1 ? qs6 : qc6) * ((T>>4)&1 ? qs7 : qc7)
                * ((T>>3)&1 ? qs8 : qc8) * ((T>>2)&1 ? qs9 : qc9)
                * ((T>>1)&1 ? qs10 : qc10) * ((T>>0)&1 ? qs11 : qc11);
        INITJC(s0,0)  INITJC(s1,1)  INITJC(s2,2)  INITJC(s3,3)
        INITJC(s4,4)  INITJC(s5,5)  INITJC(s6,6)  INITJC(s7,7)
        INITJC(s8,8)  INITJC(s9,9)  INITJC(s10,10) INITJC(s11,11)
        INITJC(s12,12) INITJC(s13,13) INITJC(s14,14) INITJC(s15,15)
        APPLY_U_K3(gU + 0 * 8);
        APPLY_UF_K2(gU + 1 * 8, gF + 0 * 8);
        APPLY_UF_K1(gU + 2 * 8, gF + 1 * 8);
        APPLY_UF_K0(gU + 3 * 8, gF + 2 * 8);
        STORW(SLC);
    }
    __syncthreads();                          // C->B crosses waves

    #pragma unroll 1
    for (int l = 0; l < DEPTH; l++) {
        const float* UL = gU + l * 96;
        const float* CL = gC + l * 22;
        const float* FL = gF + l * 72;
        // ---- window B: U4 + CRY3(pred) + fused(U5,CRY4) + fused(U6,CRY5) + fused(U7,CRY6) ----
        LOADW(SLB);
        APPLY_U_K3(UL + 4 * 8);
        if (T & 16) RYALL_K3(CL[6], CL[7]);   // CRY3 (ctrl = idx bit 8)
        APPLY_UF_K2(UL + 5 * 8, FL + 3 * 8);
        APPLY_UF_K1(UL + 6 * 8, FL + 4 * 8);
        APPLY_UF_K0(UL + 7 * 8, FL + 5 * 8);
        STORW(SLB);
        __builtin_amdgcn_wave_barrier();      // B->A is wave-private
        // ---- window A: U8 + CRY7(pred) + fused(U9,CRY8) + fused(U10,CRY9) + fused(U11,CRY10) ----
        LOADA;
        APPLY_U_K3(UL + 8 * 8);
        if (T & 1) RYALL_K3(CL[14], CL[15]);  // CRY7 (ctrl = idx bit 4)
        APPLY_UF_K2(UL + 9 * 8, FL + 6 * 8);
        APPLY_UF_K1(UL + 10 * 8, FL + 7 * 8);
        APPLY_UF_K0(UL + 11 * 8, FL + 8 * 8);
        if (l < DEPTH - 1) {
            STORA;
            __syncthreads();                  // A->C crosses waves
            // ---- window C, layer l+1: U0 + fused CRY0-2 ----
            const float* UN = gU + (l + 1) * 96;
            const float* FN = gF + (l + 1) * 72;
            LOADW(SLC);
            APPLY_U_K3(UN + 0 * 8);
            APPLY_UF_K2(UN + 1 * 8, FN + 0 * 8);
            APPLY_UF_K1(UN + 2 * 8, FN + 1 * 8);
            APPLY_UF_K0(UN + 3 * 8, FN + 2 * 8);
            STORW(SLC);
            __syncthreads();                  // C->B crosses waves
        }
    }

    // ---- marginals from registers (window A: idx = T<<4 | m) ----
    float p0 = PRJ(s0),  p1 = PRJ(s1),  p2 = PRJ(s2),  p3 = PRJ(s3);
    float p4 = PRJ(s4),  p5 = PRJ(s5),  p6 = PRJ(s6),  p7 = PRJ(s7);
    float p8 = PRJ(s8),  p9 = PRJ(s9),  p10 = PRJ(s10), p11 = PRJ(s11);
    float p12 = PRJ(s12), p13 = PRJ(s13), p14 = PRJ(s14), p15 = PRJ(s15);
    float tot = p0+p1+p2+p3+p4+p5+p6+p7+p8+p9+p10+p11+p12+p13+p14+p15;
    float r8  = p8+p9+p10+p11+p12+p13+p14+p15;
    float r9  = p4+p5+p6+p7+p12+p13+p14+p15;
    float r10 = p2+p3+p6+p7+p10+p11+p14+p15;
    float r11 = p1+p3+p5+p7+p9+p11+p13+p15;
    float r0 = (T & 128) ? tot : 0.f;
    float r1 = (T & 64)  ? tot : 0.f;
    float r2 = (T & 32)  ? tot : 0.f;
    float r3 = (T & 16)  ? tot : 0.f;
    float r4 = (T & 8)   ? tot : 0.f;
    float r5 = (T & 4)   ? tot : 0.f;
    float r6 = (T & 2)   ? tot : 0.f;
    float r7 = (T & 1)   ? tot : 0.f;

    WREDUCE(r0) WREDUCE(r1) WREDUCE(r2) WREDUCE(r3) WREDUCE(r4) WREDUCE(r5)
    WREDUCE(r6) WREDUCE(r7) WREDUCE(r8) WREDUCE(r9) WREDUCE(r10) WREDUCE(r11)

    __syncthreads();                     // xch no longer needed as state
    float* red = (float*)xch;
    int lane = T & 63, w = T >> 6;
    if (lane == 0) {
        float* rr = red + w * NQ;
        rr[0]=r0; rr[1]=r1; rr[2]=r2; rr[3]=r3; rr[4]=r4; rr[5]=r5;
        rr[6]=r6; rr[7]=r7; rr[8]=r8; rr[9]=r9; rr[10]=r10; rr[11]=r11;
    }
    __syncthreads();
    if (T < NQ) probs[b * NQ + T] = red[T] + red[NQ + T] + red[2 * NQ + T] + red[3 * NQ + T];
}

// ================= K4: prob moments -> pmean + cov (one pass) =================
__global__ void k_pcov(const float* __restrict__ probs, float* __restrict__ pmean,
                       float* __restrict__ cov) {
    __shared__ float scr[8];
    int blk = blockIdx.x;             // 0..143
    int q = blk / NQ, q2 = blk % NQ;
    int t = threadIdx.x;
    float sx = 0.f, sy = 0.f, sxy = 0.f;
    for (int b = t; b < BATCH; b += 256) {
        float xv = probs[b * NQ + q];
        float yv = probs[b * NQ + q2];
        sx += xv; sy += yv; sxy += xv * yv;
    }
    float SX  = blockAllSum(sx,  scr);
    float SY  = blockAllSum(sy,  scr);
    float SXY = blockAllSum(sxy, scr);
    if (t == 0) {
        float mx = SX / (float)BATCH, my = SY / (float)BATCH;
        cov[blk] = SXY / (float)BATCH - mx * my;
        if (q == q2) pmean[q] = mx;
    }
}

// ================= K5: rstd per output feature (1 block) =================
__global__ void k_rstd(const float* __restrict__ cov, const float* __restrict__ dw,
                       float* __restrict__ rstd) {
    __shared__ float cv[NQ * NQ];
    int t = threadIdx.x;
    if (t < NQ * NQ) cv[t] = cov[t];
    __syncthreads();
    float w[NQ];
    #pragma unroll
    for (int q = 0; q < NQ; q++) w[q] = dw[t * NQ + q];
    float var = 0.f;
    #pragma unroll
    for (int q = 0; q < NQ; q++) {
        float a = 0.f;
        #pragma unroll
        for (int q2 = 0; q2 < NQ; q2++) a += cv[q * NQ + q2] * w[q2];
        var += w[q] * a;
    }
    rstd[t] = 1.f / sqrtf(var + BN_EPS);
}

// ================= K6: final decode + BN2 (2 rows per block) =================
__global__ void k_final(const float* __restrict__ probs, const float* __restrict__ pmean,
                        const float* __restrict__ rstd, const float* __restrict__ dw,
                        const float* __restrict__ g2, const float* __restrict__ b2,
                        float* __restrict__ out) {
    __shared__ float cp[2][NQ];
    int b0 = blockIdx.x * 2;
    int t = threadIdx.x;
    int half = t >> 8, j = t & 255;
    if (t < NQ)                      cp[0][t]       = probs[b0 * NQ + t]        - pmean[t];
    else if (t >= 256 && t < 256+NQ) cp[1][t - 256] = probs[(b0+1) * NQ + t-256] - pmean[t - 256];
    __syncthreads();
    float acc = 0.f;
    #pragma unroll
    for (int q = 0; q < NQ; q++) acc += cp[half][q] * dw[j * NQ + q];
    out[(b0 + half) * OUT_SZ + j] = acc * rstd[j] * g2[j] + b2[j];
}

extern "C" void kernel_launch(void* const* d_in, const int* in_sizes, int n_in,
                              void* d_out, int out_size, void* d_ws, size_t ws_size,
                              hipStream_t stream) {
    const float* x     = (const float*)d_in[0];
    const float* enc_w = (const float*)d_in[1];
    const float* enc_b = (const float*)d_in[2];
    const float* rot   = (const float*)d_in[3];
    const float* ent   = (const float*)d_in[4];
    const float* dec_w = (const float*)d_in[5];
    // d_in[6] = dec_b — cancels inside BN2
    const float* g1    = (const float*)d_in[7];
    const float* b1    = (const float*)d_in[8];
    const float* g2    = (const float*)d_in[9];
    const float* b2    = (const float*)d_in[10];

    float* ws    = (float*)d_ws;
    float* enc   = ws + OFF_ENC;
    float* bn1m  = ws + OFF_BN1M;
    float* bn1r  = ws + OFF_BN1R;
    float* gU    = ws + OFF_GU;
    float* gC    = ws + OFF_GC;
    float* gF    = ws + OFF_GF;
    float* prb   = ws + OFF_PROBS;
    float* pmean = ws + OFF_PMEAN;
    float* cov   = ws + OFF_COV;
    float* rstd  = ws + OFF_RSTD;

    hipLaunchKernelGGL(k_encode, dim3(1025), dim3(256), 0, stream,
                       x, enc_w, enc_b, rot, ent, enc, gU, gC, gF);
    hipLaunchKernelGGL(k_bnstats, dim3(NQ), dim3(1024), 0, stream, enc, bn1m, bn1r);
    hipLaunchKernelGGL(k_quantum, dim3(BATCH), dim3(256), 0, stream,
                       enc, bn1m, bn1r, g1, b1, gU, gC, gF, prb);
    hipLaunchKernelGGL(k_pcov, dim3(NQ * NQ), dim3(256), 0, stream, prb, pmean, cov);
    hipLaunchKernelGGL(k_rstd, dim3(1), dim3(OUT_SZ), 0, stream, cov, dec_w, rstd);
    hipLaunchKernelGGL(k_final, dim3(BATCH / 2), dim3(512), 0, stream,
                       prb, pmean, rstd, dec_w, g2, b2, (float*)d_out);
}